// Round 14
// baseline (193.201 us; speedup 1.0000x reference)
//
#include <hip/hip_runtime.h>
#include <hip/hip_bf16.h>
#include <math.h>

#define N_NODES 50000
#define N_EDGES 800000
#define NEG_SLOPE 0.2f
#define EPS_DEN 1e-9f

constexpr int SCAN_BLK = 1024;
constexpr int NB_SCAN = (N_NODES + SCAN_BLK - 1) / SCAN_BLK;   // 49
constexpr int NB_EDGE = (N_EDGES + 255) / 256;                  // 3125
constexpr int ROWS_A  = 25024;                                  // half-A rows (64-aligned)
constexpr int NB_GA   = ROWS_A / 64;                            // 391
constexpr int NB_GB   = (N_NODES - ROWS_A + 63) / 64;           // 391
constexpr int NB_INIT = (N_NODES + 255) / 256;                  // 196 (>= 128 for Wt)

typedef __attribute__((ext_vector_type(8))) short short8v;
typedef __attribute__((ext_vector_type(4))) float f32x4;
typedef __attribute__((ext_vector_type(2))) float f32x2;

__device__ inline unsigned short f2bf(float x) {
    __hip_bfloat16 h = __float2bfloat16(x);
    return *(unsigned short*)&h;
}
__device__ inline float bflo(unsigned int u) { return __uint_as_float(u << 16); }
__device__ inline float bfhi(unsigned int u) { return __uint_as_float(u & 0xffff0000u); }
__device__ inline float leaky(float x) { return x > 0.f ? x : NEG_SLOPE * x; }

// ---------------- K1: zero deg ∥ build Wt[col][k] = bf16(W1[k][col]) ----------------

__global__ void init_k(int* __restrict__ deg, const float* __restrict__ W,
                       unsigned short* __restrict__ Wt) {
    int i = blockIdx.x * 256 + threadIdx.x;
    if (i < N_NODES) deg[i] = 0;
    if (i < 128 * 256) {
        int col = i >> 8, k = i & 255;
        Wt[i] = f2bf(W[(size_t)k * 128 + col]);
    }
}

// ---------------- scan ----------------

__global__ void scan1_k(const int* __restrict__ deg, int* __restrict__ off,
                        int* __restrict__ bsum) {
    __shared__ int sh[256];
    int b = blockIdx.x, t = threadIdx.x;
    int base = b * SCAN_BLK + t * 4;
    int v[4]; int s = 0;
    #pragma unroll
    for (int i = 0; i < 4; ++i) {
        int idx = base + i;
        v[i] = (idx < N_NODES) ? deg[idx] : 0;
        s += v[i];
    }
    sh[t] = s; __syncthreads();
    for (int ofs = 1; ofs < 256; ofs <<= 1) {
        int x = 0;
        if (t >= ofs) x = sh[t - ofs];
        __syncthreads();
        sh[t] += x;
        __syncthreads();
    }
    int excl = sh[t] - s;
    if (t == 255) bsum[b] = sh[255];
    int run = excl;
    #pragma unroll
    for (int i = 0; i < 4; ++i) {
        int idx = base + i;
        if (idx < N_NODES) off[idx] = run;
        run += v[i];
    }
}

// merged scan2+scan3; also initializes cursor
__global__ void scan3_k(int* __restrict__ off, int* __restrict__ cursor,
                        const int* __restrict__ bsum) {
    __shared__ int pre;
    int b = blockIdx.x;
    if (threadIdx.x == 0) {
        int s = 0;
        int nb = b >> 2;
        for (int j = 0; j < nb; ++j) s += bsum[j];
        pre = s;
    }
    __syncthreads();
    int i = b * 256 + threadIdx.x;
    if (i < N_NODES) {
        int v = off[i] + pre;
        off[i] = v;
        cursor[i] = v;
    }
    if (i == 0) off[N_NODES] = N_EDGES;
}

// ---------------- gemm body (MFMA, zero-LDS, 64-row tile) + fused el1/er1 ----------------

__device__ inline void gemm_body(int rowBase0,
                                 const float* __restrict__ H,
                                 const unsigned short* __restrict__ Wt,
                                 const float* __restrict__ AL,
                                 const float* __restrict__ AR,
                                 unsigned short* __restrict__ Fb,
                                 float* __restrict__ el, float* __restrict__ er) {
    int t = threadIdx.x;
    int w = t >> 6, l = t & 63;
    int lr = l & 15, lk = l >> 4;
    int rowBase = rowBase0 + w * 16;
    f32x4 acc[8] = {};

    int arow = min(rowBase + lr, N_NODES - 1);     // clamp: loads unconditional
    const float4* Hrow = (const float4*)&H[(size_t)arow * 256 + lk * 8];

    float4 hv[16];
    #pragma unroll
    for (int kc = 0; kc < 8; ++kc) {
        hv[2 * kc]     = Hrow[(size_t)kc * 8];
        hv[2 * kc + 1] = Hrow[(size_t)kc * 8 + 1];
    }

    #pragma unroll
    for (int kc = 0; kc < 8; ++kc) {
        int k0 = kc * 32 + lk * 8;
        union { unsigned u[4]; short8v v; } ah, alo;
        const float* f = (const float*)&hv[2 * kc];
        #pragma unroll
        for (int j = 0; j < 4; ++j) {
            float f0 = f[2 * j], f1 = f[2 * j + 1];
            unsigned b0 = __float_as_uint(f0);
            unsigned b1 = __float_as_uint(f1);
            ah.u[j] = __builtin_amdgcn_perm(b1, b0, 0x07060302u);
            float r0 = f0 - __uint_as_float(b0 & 0xffff0000u);
            float r1 = f1 - __uint_as_float(b1 & 0xffff0000u);
            alo.u[j] = __builtin_amdgcn_perm(__float_as_uint(r1), __float_as_uint(r0),
                                             0x07060302u);
        }
        #pragma unroll
        for (int cf = 0; cf < 8; ++cf) {
            short8v b = *(const short8v*)&Wt[(size_t)(cf * 16 + lr) * 256 + k0];
            acc[cf] = __builtin_amdgcn_mfma_f32_16x16x32_bf16(ah.v,  b, acc[cf], 0, 0, 0);
            acc[cf] = __builtin_amdgcn_mfma_f32_16x16x32_bf16(alo.v, b, acc[cf], 0, 0, 0);
        }
    }

    #pragma unroll
    for (int r = 0; r < 4; ++r) {
        int row = rowBase + lk * 4 + r;
        if (row < N_NODES) {
            #pragma unroll
            for (int cf = 0; cf < 8; ++cf)
                Fb[(size_t)row * 128 + cf * 16 + lr] = f2bf(acc[cf][r]);
        }
    }

    float pel[4][4], per_[4][4];
    #pragma unroll
    for (int hh = 0; hh < 4; ++hh) {
        float a0 = AL[hh * 32 + lr], a1 = AL[hh * 32 + 16 + lr];
        float r0 = AR[hh * 32 + lr], r1 = AR[hh * 32 + 16 + lr];
        #pragma unroll
        for (int r = 0; r < 4; ++r) {
            pel[hh][r]  = acc[2 * hh][r] * a0 + acc[2 * hh + 1][r] * a1;
            per_[hh][r] = acc[2 * hh][r] * r0 + acc[2 * hh + 1][r] * r1;
        }
    }
    #pragma unroll
    for (int m = 1; m <= 8; m <<= 1) {
        #pragma unroll
        for (int hh = 0; hh < 4; ++hh)
            #pragma unroll
            for (int r = 0; r < 4; ++r) {
                pel[hh][r]  += __shfl_xor(pel[hh][r], m, 64);
                per_[hh][r] += __shfl_xor(per_[hh][r], m, 64);
            }
    }
    if (lr == 0) {
        #pragma unroll
        for (int r = 0; r < 4; ++r) {
            int row = rowBase + lk * 4 + r;
            if (row < N_NODES) {
                #pragma unroll
                for (int hh = 0; hh < 4; ++hh) {
                    el[(size_t)row * 4 + hh] = pel[hh][r];
                    er[(size_t)row * 4 + hh] = per_[hh][r];
                }
            }
        }
    }
}

// ---------------- K2: gemm half A ∥ count ----------------

__global__ __launch_bounds__(256) void gemmA_count_k(
        const float* __restrict__ H, const unsigned short* __restrict__ Wt,
        const float* __restrict__ AL, const float* __restrict__ AR,
        unsigned short* __restrict__ Fb, float* __restrict__ el, float* __restrict__ er,
        const int* __restrict__ dst, int* __restrict__ deg) {
    int bx = blockIdx.x;
    if (bx < NB_GA) {
        gemm_body(bx * 64, H, Wt, AL, AR, Fb, el, er);
    } else {
        int e = (bx - NB_GA) * 256 + threadIdx.x;
        if (e < N_EDGES) atomicAdd(&deg[dst[e]], 1);
    }
}

// ---------------- K5: gemm half B ∥ scatter (nt csr stores: no L2 write-allocate) ----------------

__global__ __launch_bounds__(256) void gemmB_scatter_k(
        const float* __restrict__ H, const unsigned short* __restrict__ Wt,
        const float* __restrict__ AL, const float* __restrict__ AR,
        unsigned short* __restrict__ Fb, float* __restrict__ el, float* __restrict__ er,
        const int* __restrict__ src, const int* __restrict__ dst,
        int* __restrict__ cursor, int* __restrict__ csr) {
    int bx = blockIdx.x;
    if (bx < NB_GB) {
        gemm_body(ROWS_A + bx * 64, H, Wt, AL, AR, Fb, el, er);
    } else {
        int e = (bx - NB_GB) * 256 + threadIdx.x;
        if (e < N_EDGES) {
            int s = src[e];
            int p = atomicAdd(&cursor[dst[e]], 1);
            __builtin_nontemporal_store(s, &csr[p]);
        }
    }
}

// ---------------- agg1: wave-per-node, pair-pipelined clamped gathers, pk-f32 math ----------------
// wave lanes: g = slot 0..3, l = dim group 0..15 (dims 8l..8l+7), head l>>2.

__global__ __launch_bounds__(256) void agg1_k(const unsigned short* __restrict__ Fb,
                                              const int* __restrict__ off,
                                              const int* __restrict__ csr,
                                              const float* __restrict__ el1,
                                              const float* __restrict__ er1,
                                              const float* __restrict__ b1,
                                              const float* __restrict__ W2,
                                              const float* __restrict__ al2,
                                              const float* __restrict__ ar2,
                                              unsigned short* __restrict__ feat2b,
                                              float* __restrict__ el2,
                                              float* __restrict__ er2) {
    __shared__ float h1row[4][128];
    int wid = threadIdx.x >> 6;
    int n = blockIdx.x * 4 + wid;
    if (n >= N_NODES) return;
    int t = threadIdx.x & 63;
    int g = t >> 4;
    int l = t & 15;
    int hh = l >> 2;
    int e0 = off[n], e1 = off[n + 1];
    int deg = e1 - e0;
    int niter = (deg + 7) >> 3;          // wave-uniform
    float ern = er1[(size_t)n * 4 + hh];

    f32x2 A0 = {0.f, 0.f}, A1 = A0, A2 = A0, A3 = A0;
    float dsum = 0.f;

    int eA = e0 + g;
    float xA = 0.f, xB = 0.f;
    uint4 uA = {0u,0u,0u,0u}, uB = {0u,0u,0u,0u};
    if (niter > 0) {                      // uniform branch
        int ec = min(eA, N_EDGES - 1);
        int s = csr[ec];
        xA = el1[(size_t)s * 4 + hh];
        uA = *(const uint4*)&Fb[(size_t)s * 128 + l * 8];
        ec = min(eA + 4, N_EDGES - 1);
        s = csr[ec];
        xB = el1[(size_t)s * 4 + hh];
        uB = *(const uint4*)&Fb[(size_t)s * 128 + l * 8];
    }
    for (int i = 0; i < niter; ++i) {
        float xA2 = 0.f, xB2 = 0.f;
        uint4 uA2 = {0u,0u,0u,0u}, uB2 = {0u,0u,0u,0u};
        if (i + 1 < niter) {              // uniform branch
            int e = eA + 8 * (i + 1);
            int ec = min(e, N_EDGES - 1);
            int s = csr[ec];
            xA2 = el1[(size_t)s * 4 + hh];
            uA2 = *(const uint4*)&Fb[(size_t)s * 128 + l * 8];
            ec = min(e + 4, N_EDGES - 1);
            s = csr[ec];
            xB2 = el1[(size_t)s * 4 + hh];
            uB2 = *(const uint4*)&Fb[(size_t)s * 128 + l * 8];
        }
        int ebase = eA + 8 * i;
        float wA = (ebase     < e1) ? __expf(leaky(xA + ern)) : 0.f;
        float wB = (ebase + 4 < e1) ? __expf(leaky(xB + ern)) : 0.f;
        {
            f32x2 W = {wA, wA};
            f32x2 q0 = {bflo(uA.x), bfhi(uA.x)}, q1 = {bflo(uA.y), bfhi(uA.y)};
            f32x2 q2 = {bflo(uA.z), bfhi(uA.z)}, q3 = {bflo(uA.w), bfhi(uA.w)};
            A0 += W * q0; A1 += W * q1; A2 += W * q2; A3 += W * q3;
        }
        {
            f32x2 W = {wB, wB};
            f32x2 q0 = {bflo(uB.x), bfhi(uB.x)}, q1 = {bflo(uB.y), bfhi(uB.y)};
            f32x2 q2 = {bflo(uB.z), bfhi(uB.z)}, q3 = {bflo(uB.w), bfhi(uB.w)};
            A0 += W * q0; A1 += W * q1; A2 += W * q2; A3 += W * q3;
        }
        dsum += wA + wB;
        xA = xA2; xB = xB2; uA = uA2; uB = uB2;
    }

    float a0 = A0.x, a1 = A0.y, a2 = A1.x, a3 = A1.y;
    float a4 = A2.x, a5 = A2.y, a6 = A3.x, a7 = A3.y;
    #pragma unroll
    for (int m = 16; m <= 32; m <<= 1) {
        a0 += __shfl_xor(a0, m, 64); a1 += __shfl_xor(a1, m, 64);
        a2 += __shfl_xor(a2, m, 64); a3 += __shfl_xor(a3, m, 64);
        a4 += __shfl_xor(a4, m, 64); a5 += __shfl_xor(a5, m, 64);
        a6 += __shfl_xor(a6, m, 64); a7 += __shfl_xor(a7, m, 64);
        dsum += __shfl_xor(dsum, m, 64);
    }

    float inv = 1.f / (dsum + EPS_DEN);
    float o[8] = {a0, a1, a2, a3, a4, a5, a6, a7};
    #pragma unroll
    for (int j = 0; j < 8; ++j) {
        float v = fmaf(o[j], inv, b1[l * 8 + j]);
        o[j] = v > 0.f ? v : __expf(v) - 1.f;
    }
    if (g == 0) {
        *(float4*)&h1row[wid][l * 8]     = make_float4(o[0], o[1], o[2], o[3]);
        *(float4*)&h1row[wid][l * 8 + 4] = make_float4(o[4], o[5], o[6], o[7]);
    }
    // wave-coherent LDS RAW within the same wave

    // fused GEMM2, j-quad form: lane = 4 cols (jq) x 16 k's (kb2)
    int jq = (t & 7) * 4;
    int kb2 = (t >> 3) * 16;
    float p0 = 0.f, p1 = 0.f, p2 = 0.f, p3 = 0.f;
    #pragma unroll
    for (int k = 0; k < 16; ++k) {
        float hv = h1row[wid][kb2 + k];
        float4 wv = *(const float4*)&W2[(size_t)(kb2 + k) * 32 + jq];
        p0 = fmaf(hv, wv.x, p0);
        p1 = fmaf(hv, wv.y, p1);
        p2 = fmaf(hv, wv.z, p2);
        p3 = fmaf(hv, wv.w, p3);
    }
    #pragma unroll
    for (int m = 8; m <= 32; m <<= 1) {
        p0 += __shfl_xor(p0, m, 64);
        p1 += __shfl_xor(p1, m, 64);
        p2 += __shfl_xor(p2, m, 64);
        p3 += __shfl_xor(p3, m, 64);
    }
    if (t < 8) {
        ushort4 fv = {f2bf(p0), f2bf(p1), f2bf(p2), f2bf(p3)};
        *(ushort4*)&feat2b[(size_t)n * 32 + jq] = fv;
        float sl = p0 * al2[jq] + p1 * al2[jq + 1] + p2 * al2[jq + 2] + p3 * al2[jq + 3];
        float sr = p0 * ar2[jq] + p1 * ar2[jq + 1] + p2 * ar2[jq + 2] + p3 * ar2[jq + 3];
        #pragma unroll
        for (int m = 1; m <= 4; m <<= 1) {
            sl += __shfl_xor(sl, m, 64);
            sr += __shfl_xor(sr, m, 64);
        }
        if (t == 0) { el2[n] = sl; er2[n] = sr; }
    }
}

// ---------------- agg2: wave-per-node, uniform-iter clamped gathers, pk-f32 math ----------------
// 16 edge slots x 4 dim lanes (dims 8l..8l+7)

__global__ __launch_bounds__(256) void agg2_k(const unsigned short* __restrict__ F2b,
                                              const int* __restrict__ off,
                                              const int* __restrict__ csr,
                                              const float* __restrict__ el2,
                                              const float* __restrict__ er2,
                                              const float* __restrict__ b2,
                                              float* __restrict__ out) {
    int wid = threadIdx.x >> 6;
    int n = blockIdx.x * 4 + wid;
    if (n >= N_NODES) return;
    int t = threadIdx.x & 63;
    int g = t >> 2, l = t & 3;
    int e0 = off[n], e1 = off[n + 1];
    int deg = e1 - e0;
    int niter = (deg + 15) >> 4;         // wave-uniform
    float ern = er2[n];

    f32x2 A0 = {0.f, 0.f}, A1 = A0, A2 = A0, A3 = A0;
    float dsum = 0.f;

    int eG = e0 + g;
    float x = 0.f;
    uint4 u = {0u,0u,0u,0u};
    if (niter > 0) {
        int ec = min(eG, N_EDGES - 1);
        int s = csr[ec];
        x = el2[s];
        u = *(const uint4*)&F2b[(size_t)s * 32 + l * 8];
    }
    for (int i = 0; i < niter; ++i) {
        float x2 = 0.f;
        uint4 u2 = {0u,0u,0u,0u};
        if (i + 1 < niter) {
            int e = eG + 16 * (i + 1);
            int ec = min(e, N_EDGES - 1);
            int s = csr[ec];
            x2 = el2[s];
            u2 = *(const uint4*)&F2b[(size_t)s * 32 + l * 8];
        }
        float w = (eG + 16 * i < e1) ? __expf(leaky(x + ern)) : 0.f;
        {
            f32x2 W = {w, w};
            f32x2 q0 = {bflo(u.x), bfhi(u.x)}, q1 = {bflo(u.y), bfhi(u.y)};
            f32x2 q2 = {bflo(u.z), bfhi(u.z)}, q3 = {bflo(u.w), bfhi(u.w)};
            A0 += W * q0; A1 += W * q1; A2 += W * q2; A3 += W * q3;
        }
        dsum += w;
        x = x2; u = u2;
    }
    float a0 = A0.x, a1 = A0.y, a2 = A1.x, a3 = A1.y;
    float a4 = A2.x, a5 = A2.y, a6 = A3.x, a7 = A3.y;
    #pragma unroll
    for (int m = 4; m <= 32; m <<= 1) {
        a0 += __shfl_xor(a0, m, 64); a1 += __shfl_xor(a1, m, 64);
        a2 += __shfl_xor(a2, m, 64); a3 += __shfl_xor(a3, m, 64);
        a4 += __shfl_xor(a4, m, 64); a5 += __shfl_xor(a5, m, 64);
        a6 += __shfl_xor(a6, m, 64); a7 += __shfl_xor(a7, m, 64);
        dsum += __shfl_xor(dsum, m, 64);
    }
    if (t < 4) {
        float inv = 1.f / (dsum + EPS_DEN);
        float4 r0, r1;
        r0.x = fmaf(a0, inv, b2[l * 8 + 0]);
        r0.y = fmaf(a1, inv, b2[l * 8 + 1]);
        r0.z = fmaf(a2, inv, b2[l * 8 + 2]);
        r0.w = fmaf(a3, inv, b2[l * 8 + 3]);
        r1.x = fmaf(a4, inv, b2[l * 8 + 4]);
        r1.y = fmaf(a5, inv, b2[l * 8 + 5]);
        r1.z = fmaf(a6, inv, b2[l * 8 + 6]);
        r1.w = fmaf(a7, inv, b2[l * 8 + 7]);
        *(float4*)&out[(size_t)n * 32 + l * 8]     = r0;
        *(float4*)&out[(size_t)n * 32 + l * 8 + 4] = r1;
    }
}

// ---------------- launch ----------------

extern "C" void kernel_launch(void* const* d_in, const int* in_sizes, int n_in,
                              void* d_out, int out_size, void* d_ws, size_t ws_size,
                              hipStream_t stream) {
    const float* h   = (const float*)d_in[0];
    const float* W1  = (const float*)d_in[1];
    const float* al1 = (const float*)d_in[2];
    const float* ar1 = (const float*)d_in[3];
    const float* b1  = (const float*)d_in[4];
    const float* W2  = (const float*)d_in[5];
    const float* al2 = (const float*)d_in[6];
    const float* ar2 = (const float*)d_in[7];
    const float* b2  = (const float*)d_in[8];
    const int* src   = (const int*)d_in[9];
    const int* dst   = (const int*)d_in[10];
    float* out = (float*)d_out;

    char* wsb = (char*)d_ws;
    size_t o = 0;
    auto alloc = [&](size_t bytes) {
        void* p = wsb + o;
        o += (bytes + 255) & ~(size_t)255;
        return p;
    };
    int* deg     = (int*)alloc((size_t)N_NODES * 4);
    int* off     = (int*)alloc((size_t)(N_NODES + 1) * 4);
    int* cursor  = (int*)alloc((size_t)N_NODES * 4);
    int* csr     = (int*)alloc((size_t)N_EDGES * 4);
    int* bsum    = (int*)alloc((size_t)NB_SCAN * 4);
    unsigned short* Wt     = (unsigned short*)alloc((size_t)128 * 256 * 2);
    unsigned short* feat1b = (unsigned short*)alloc((size_t)N_NODES * 128 * 2);
    float* el1   = (float*)alloc((size_t)N_NODES * 4 * 4);
    float* er1   = (float*)alloc((size_t)N_NODES * 4 * 4);
    unsigned short* feat2b = (unsigned short*)alloc((size_t)N_NODES * 32 * 2);
    float* el2   = (float*)alloc((size_t)N_NODES * 4);
    float* er2   = (float*)alloc((size_t)N_NODES * 4);

    init_k<<<NB_INIT, 256, 0, stream>>>(deg, W1, Wt);
    gemmA_count_k<<<NB_GA + NB_EDGE, 256, 0, stream>>>(h, Wt, al1, ar1, feat1b,
                                                       el1, er1, dst, deg);
    scan1_k<<<NB_SCAN, 256, 0, stream>>>(deg, off, bsum);
    scan3_k<<<(N_NODES + 255) / 256, 256, 0, stream>>>(off, cursor, bsum);
    gemmB_scatter_k<<<NB_GB + NB_EDGE, 256, 0, stream>>>(h, Wt, al1, ar1, feat1b,
                                                         el1, er1, src, dst, cursor, csr);
    agg1_k<<<(N_NODES + 3) / 4, 256, 0, stream>>>(feat1b, off, csr, el1, er1, b1, W2,
                                                  al2, ar2, feat2b, el2, er2);
    agg2_k<<<(N_NODES + 3) / 4, 256, 0, stream>>>(feat2b, off, csr, el2, er2, b2, out);
}

// Round 15
// 190.938 us; speedup vs baseline: 1.0119x; 1.0119x over previous
//
#include <hip/hip_runtime.h>
#include <hip/hip_bf16.h>
#include <math.h>

#define N_NODES 50000
#define N_EDGES 800000
#define NEG_SLOPE 0.2f
#define EPS_DEN 1e-9f

constexpr int SCAN_BLK = 1024;
constexpr int NB_SCAN = (N_NODES + SCAN_BLK - 1) / SCAN_BLK;   // 49
constexpr int NB_EDGE = (N_EDGES + 255) / 256;                  // 3125
constexpr int ROWS_A  = 25024;                                  // half-A rows (64-aligned)
constexpr int NB_GA   = ROWS_A / 64;                            // 391
constexpr int NB_GB   = (N_NODES - ROWS_A + 63) / 64;           // 391
constexpr int NB_INIT = (N_NODES + 255) / 256;                  // 196 (>= 128 for Wt)

typedef __attribute__((ext_vector_type(8))) short short8v;
typedef __attribute__((ext_vector_type(4))) float f32x4;

__device__ inline unsigned short f2bf(float x) {
    __hip_bfloat16 h = __float2bfloat16(x);
    return *(unsigned short*)&h;
}
__device__ inline float bflo(unsigned int u) { return __uint_as_float(u << 16); }
__device__ inline float bfhi(unsigned int u) { return __uint_as_float(u & 0xffff0000u); }
__device__ inline float leaky(float x) { return x > 0.f ? x : NEG_SLOPE * x; }

// ---------------- K1: zero deg ∥ build Wt[col][k] = bf16(W1[k][col]) ----------------

__global__ void init_k(int* __restrict__ deg, const float* __restrict__ W,
                       unsigned short* __restrict__ Wt) {
    int i = blockIdx.x * 256 + threadIdx.x;
    if (i < N_NODES) deg[i] = 0;
    if (i < 128 * 256) {
        int col = i >> 8, k = i & 255;
        Wt[i] = f2bf(W[(size_t)k * 128 + col]);
    }
}

// ---------------- scan ----------------

__global__ void scan1_k(const int* __restrict__ deg, int* __restrict__ off,
                        int* __restrict__ bsum) {
    __shared__ int sh[256];
    int b = blockIdx.x, t = threadIdx.x;
    int base = b * SCAN_BLK + t * 4;
    int v[4]; int s = 0;
    #pragma unroll
    for (int i = 0; i < 4; ++i) {
        int idx = base + i;
        v[i] = (idx < N_NODES) ? deg[idx] : 0;
        s += v[i];
    }
    sh[t] = s; __syncthreads();
    for (int ofs = 1; ofs < 256; ofs <<= 1) {
        int x = 0;
        if (t >= ofs) x = sh[t - ofs];
        __syncthreads();
        sh[t] += x;
        __syncthreads();
    }
    int excl = sh[t] - s;
    if (t == 255) bsum[b] = sh[255];
    int run = excl;
    #pragma unroll
    for (int i = 0; i < 4; ++i) {
        int idx = base + i;
        if (idx < N_NODES) off[idx] = run;
        run += v[i];
    }
}

// merged scan2+scan3; also initializes cursor
__global__ void scan3_k(int* __restrict__ off, int* __restrict__ cursor,
                        const int* __restrict__ bsum) {
    __shared__ int pre;
    int b = blockIdx.x;
    if (threadIdx.x == 0) {
        int s = 0;
        int nb = b >> 2;
        for (int j = 0; j < nb; ++j) s += bsum[j];
        pre = s;
    }
    __syncthreads();
    int i = b * 256 + threadIdx.x;
    if (i < N_NODES) {
        int v = off[i] + pre;
        off[i] = v;
        cursor[i] = v;
    }
    if (i == 0) off[N_NODES] = N_EDGES;
}

// ---------------- gemm body (MFMA, zero-LDS, 64-row tile) + fused el1/er1 ----------------

__device__ inline void gemm_body(int rowBase0,
                                 const float* __restrict__ H,
                                 const unsigned short* __restrict__ Wt,
                                 const float* __restrict__ AL,
                                 const float* __restrict__ AR,
                                 unsigned short* __restrict__ Fb,
                                 float* __restrict__ el, float* __restrict__ er) {
    int t = threadIdx.x;
    int w = t >> 6, l = t & 63;
    int lr = l & 15, lk = l >> 4;
    int rowBase = rowBase0 + w * 16;
    f32x4 acc[8] = {};

    int arow = min(rowBase + lr, N_NODES - 1);     // clamp: loads unconditional
    const float4* Hrow = (const float4*)&H[(size_t)arow * 256 + lk * 8];

    float4 hv[16];
    #pragma unroll
    for (int kc = 0; kc < 8; ++kc) {
        hv[2 * kc]     = Hrow[(size_t)kc * 8];
        hv[2 * kc + 1] = Hrow[(size_t)kc * 8 + 1];
    }

    #pragma unroll
    for (int kc = 0; kc < 8; ++kc) {
        int k0 = kc * 32 + lk * 8;
        union { unsigned u[4]; short8v v; } ah, alo;
        const float* f = (const float*)&hv[2 * kc];
        #pragma unroll
        for (int j = 0; j < 4; ++j) {
            float f0 = f[2 * j], f1 = f[2 * j + 1];
            unsigned b0 = __float_as_uint(f0);
            unsigned b1 = __float_as_uint(f1);
            ah.u[j] = __builtin_amdgcn_perm(b1, b0, 0x07060302u);
            float r0 = f0 - __uint_as_float(b0 & 0xffff0000u);
            float r1 = f1 - __uint_as_float(b1 & 0xffff0000u);
            alo.u[j] = __builtin_amdgcn_perm(__float_as_uint(r1), __float_as_uint(r0),
                                             0x07060302u);
        }
        #pragma unroll
        for (int cf = 0; cf < 8; ++cf) {
            short8v b = *(const short8v*)&Wt[(size_t)(cf * 16 + lr) * 256 + k0];
            acc[cf] = __builtin_amdgcn_mfma_f32_16x16x32_bf16(ah.v,  b, acc[cf], 0, 0, 0);
            acc[cf] = __builtin_amdgcn_mfma_f32_16x16x32_bf16(alo.v, b, acc[cf], 0, 0, 0);
        }
    }

    #pragma unroll
    for (int r = 0; r < 4; ++r) {
        int row = rowBase + lk * 4 + r;
        if (row < N_NODES) {
            #pragma unroll
            for (int cf = 0; cf < 8; ++cf)
                Fb[(size_t)row * 128 + cf * 16 + lr] = f2bf(acc[cf][r]);
        }
    }

    float pel[4][4], per_[4][4];
    #pragma unroll
    for (int hh = 0; hh < 4; ++hh) {
        float a0 = AL[hh * 32 + lr], a1 = AL[hh * 32 + 16 + lr];
        float r0 = AR[hh * 32 + lr], r1 = AR[hh * 32 + 16 + lr];
        #pragma unroll
        for (int r = 0; r < 4; ++r) {
            pel[hh][r]  = acc[2 * hh][r] * a0 + acc[2 * hh + 1][r] * a1;
            per_[hh][r] = acc[2 * hh][r] * r0 + acc[2 * hh + 1][r] * r1;
        }
    }
    #pragma unroll
    for (int m = 1; m <= 8; m <<= 1) {
        #pragma unroll
        for (int hh = 0; hh < 4; ++hh)
            #pragma unroll
            for (int r = 0; r < 4; ++r) {
                pel[hh][r]  += __shfl_xor(pel[hh][r], m, 64);
                per_[hh][r] += __shfl_xor(per_[hh][r], m, 64);
            }
    }
    if (lr == 0) {
        #pragma unroll
        for (int r = 0; r < 4; ++r) {
            int row = rowBase + lk * 4 + r;
            if (row < N_NODES) {
                #pragma unroll
                for (int hh = 0; hh < 4; ++hh) {
                    el[(size_t)row * 4 + hh] = pel[hh][r];
                    er[(size_t)row * 4 + hh] = per_[hh][r];
                }
            }
        }
    }
}

// ---------------- K2: gemm half A ∥ count ----------------

__global__ __launch_bounds__(256) void gemmA_count_k(
        const float* __restrict__ H, const unsigned short* __restrict__ Wt,
        const float* __restrict__ AL, const float* __restrict__ AR,
        unsigned short* __restrict__ Fb, float* __restrict__ el, float* __restrict__ er,
        const int* __restrict__ dst, int* __restrict__ deg) {
    int bx = blockIdx.x;
    if (bx < NB_GA) {
        gemm_body(bx * 64, H, Wt, AL, AR, Fb, el, er);
    } else {
        int e = (bx - NB_GA) * 256 + threadIdx.x;
        if (e < N_EDGES) atomicAdd(&deg[dst[e]], 1);
    }
}

// ---------------- K5: gemm half B ∥ scatter ----------------

__global__ __launch_bounds__(256) void gemmB_scatter_k(
        const float* __restrict__ H, const unsigned short* __restrict__ Wt,
        const float* __restrict__ AL, const float* __restrict__ AR,
        unsigned short* __restrict__ Fb, float* __restrict__ el, float* __restrict__ er,
        const int* __restrict__ src, const int* __restrict__ dst,
        int* __restrict__ cursor, int* __restrict__ csr) {
    int bx = blockIdx.x;
    if (bx < NB_GB) {
        gemm_body(ROWS_A + bx * 64, H, Wt, AL, AR, Fb, el, er);
    } else {
        int e = (bx - NB_GB) * 256 + threadIdx.x;
        if (e < N_EDGES) {
            int p = atomicAdd(&cursor[dst[e]], 1);
            csr[p] = src[e];
        }
    }
}

// ---------------- agg1: 2 waves per node, pair-pipelined clamped gathers ----------------
// block = 256 thr = 4 waves = 2 nodes. pair p = wid>>1, sub = wid&1.
// wave lanes: g = slot 0..3, l = dim group 0..15 (dims 8l..8l+7), head l>>2.
// wave sub covers edge offsets 8*sub + g (+4), stride 16 -> 16 edges/iter/node.

__global__ __launch_bounds__(256) void agg1_k(const unsigned short* __restrict__ Fb,
                                              const int* __restrict__ off,
                                              const int* __restrict__ csr,
                                              const float* __restrict__ el1,
                                              const float* __restrict__ er1,
                                              const float* __restrict__ b1,
                                              const float* __restrict__ W2,
                                              const float* __restrict__ al2,
                                              const float* __restrict__ ar2,
                                              unsigned short* __restrict__ feat2b,
                                              float* __restrict__ el2,
                                              float* __restrict__ er2) {
    __shared__ float part[2][16][9];
    __shared__ float h1row[2][128];
    int wid = threadIdx.x >> 6;
    int p = wid >> 1, sub = wid & 1;
    int n = blockIdx.x * 2 + p;          // N_NODES even: always < N_NODES
    int t = threadIdx.x & 63;
    int g = t >> 4;
    int l = t & 15;
    int hh = l >> 2;
    int e0 = off[n], e1 = off[n + 1];
    int deg = e1 - e0;
    int niter = (deg + 15) >> 4;         // pair-uniform
    float ern = er1[(size_t)n * 4 + hh];

    float a0 = 0.f, a1 = 0.f, a2 = 0.f, a3 = 0.f, a4 = 0.f, a5 = 0.f, a6 = 0.f, a7 = 0.f;
    float dsum = 0.f;

    int eA = e0 + 8 * sub + g;
    float xA = 0.f, xB = 0.f;
    uint4 uA = {0u,0u,0u,0u}, uB = {0u,0u,0u,0u};
    if (niter > 0) {                      // uniform branch
        int ec = min(eA, N_EDGES - 1);
        int s = csr[ec];
        xA = el1[(size_t)s * 4 + hh];
        uA = *(const uint4*)&Fb[(size_t)s * 128 + l * 8];
        ec = min(eA + 4, N_EDGES - 1);
        s = csr[ec];
        xB = el1[(size_t)s * 4 + hh];
        uB = *(const uint4*)&Fb[(size_t)s * 128 + l * 8];
    }
    for (int i = 0; i < niter; ++i) {
        float xA2 = 0.f, xB2 = 0.f;
        uint4 uA2 = {0u,0u,0u,0u}, uB2 = {0u,0u,0u,0u};
        if (i + 1 < niter) {              // uniform branch
            int e = eA + 16 * (i + 1);
            int ec = min(e, N_EDGES - 1);
            int s = csr[ec];
            xA2 = el1[(size_t)s * 4 + hh];
            uA2 = *(const uint4*)&Fb[(size_t)s * 128 + l * 8];
            ec = min(e + 4, N_EDGES - 1);
            s = csr[ec];
            xB2 = el1[(size_t)s * 4 + hh];
            uB2 = *(const uint4*)&Fb[(size_t)s * 128 + l * 8];
        }
        int ebase = 8 * sub + g + 16 * i;
        float wA = (ebase     < deg) ? __expf(leaky(xA + ern)) : 0.f;
        float wB = (ebase + 4 < deg) ? __expf(leaky(xB + ern)) : 0.f;
        a0 = fmaf(wA, bflo(uA.x), a0); a1 = fmaf(wA, bfhi(uA.x), a1);
        a2 = fmaf(wA, bflo(uA.y), a2); a3 = fmaf(wA, bfhi(uA.y), a3);
        a4 = fmaf(wA, bflo(uA.z), a4); a5 = fmaf(wA, bfhi(uA.z), a5);
        a6 = fmaf(wA, bflo(uA.w), a6); a7 = fmaf(wA, bfhi(uA.w), a7);
        a0 = fmaf(wB, bflo(uB.x), a0); a1 = fmaf(wB, bfhi(uB.x), a1);
        a2 = fmaf(wB, bflo(uB.y), a2); a3 = fmaf(wB, bfhi(uB.y), a3);
        a4 = fmaf(wB, bflo(uB.z), a4); a5 = fmaf(wB, bfhi(uB.z), a5);
        a6 = fmaf(wB, bflo(uB.w), a6); a7 = fmaf(wB, bfhi(uB.w), a7);
        dsum += wA + wB;
        xA = xA2; xB = xB2; uA = uA2; uB = uB2;
    }

    #pragma unroll
    for (int m = 16; m <= 32; m <<= 1) {
        a0 += __shfl_xor(a0, m, 64); a1 += __shfl_xor(a1, m, 64);
        a2 += __shfl_xor(a2, m, 64); a3 += __shfl_xor(a3, m, 64);
        a4 += __shfl_xor(a4, m, 64); a5 += __shfl_xor(a5, m, 64);
        a6 += __shfl_xor(a6, m, 64); a7 += __shfl_xor(a7, m, 64);
        dsum += __shfl_xor(dsum, m, 64);
    }

    if (sub == 1 && g == 0) {
        part[p][l][0] = a0; part[p][l][1] = a1; part[p][l][2] = a2; part[p][l][3] = a3;
        part[p][l][4] = a4; part[p][l][5] = a5; part[p][l][6] = a6; part[p][l][7] = a7;
        part[p][l][8] = dsum;
    }
    __syncthreads();
    if (sub == 1) return;

    a0 += part[p][l][0]; a1 += part[p][l][1]; a2 += part[p][l][2]; a3 += part[p][l][3];
    a4 += part[p][l][4]; a5 += part[p][l][5]; a6 += part[p][l][6]; a7 += part[p][l][7];
    dsum += part[p][l][8];

    float inv = 1.f / (dsum + EPS_DEN);
    float o[8] = {a0, a1, a2, a3, a4, a5, a6, a7};
    #pragma unroll
    for (int j = 0; j < 8; ++j) {
        float v = fmaf(o[j], inv, b1[l * 8 + j]);
        o[j] = v > 0.f ? v : __expf(v) - 1.f;
    }
    if (g == 0) {
        *(float4*)&h1row[p][l * 8]     = make_float4(o[0], o[1], o[2], o[3]);
        *(float4*)&h1row[p][l * 8 + 4] = make_float4(o[4], o[5], o[6], o[7]);
    }
    // wave-coherent LDS RAW within the same wave

    // fused GEMM2, j-quad form: lane = 4 cols (jq) x 16 k's (kb2)
    int jq = (t & 7) * 4;
    int kb2 = (t >> 3) * 16;
    float p0 = 0.f, p1 = 0.f, p2 = 0.f, p3 = 0.f;
    #pragma unroll
    for (int k = 0; k < 16; ++k) {
        float hv = h1row[p][kb2 + k];
        float4 wv = *(const float4*)&W2[(size_t)(kb2 + k) * 32 + jq];
        p0 = fmaf(hv, wv.x, p0);
        p1 = fmaf(hv, wv.y, p1);
        p2 = fmaf(hv, wv.z, p2);
        p3 = fmaf(hv, wv.w, p3);
    }
    #pragma unroll
    for (int m = 8; m <= 32; m <<= 1) {
        p0 += __shfl_xor(p0, m, 64);
        p1 += __shfl_xor(p1, m, 64);
        p2 += __shfl_xor(p2, m, 64);
        p3 += __shfl_xor(p3, m, 64);
    }
    if (t < 8) {
        ushort4 fv = {f2bf(p0), f2bf(p1), f2bf(p2), f2bf(p3)};
        *(ushort4*)&feat2b[(size_t)n * 32 + jq] = fv;
        float sl = p0 * al2[jq] + p1 * al2[jq + 1] + p2 * al2[jq + 2] + p3 * al2[jq + 3];
        float sr = p0 * ar2[jq] + p1 * ar2[jq + 1] + p2 * ar2[jq + 2] + p3 * ar2[jq + 3];
        #pragma unroll
        for (int m = 1; m <= 4; m <<= 1) {
            sl += __shfl_xor(sl, m, 64);
            sr += __shfl_xor(sr, m, 64);
        }
        if (t == 0) { el2[n] = sl; er2[n] = sr; }
    }
}

// ---------------- agg2: wave-per-node, uniform-iter clamped gathers ----------------
// 16 edge slots x 4 dim lanes (dims 8l..8l+7)

__global__ __launch_bounds__(256) void agg2_k(const unsigned short* __restrict__ F2b,
                                              const int* __restrict__ off,
                                              const int* __restrict__ csr,
                                              const float* __restrict__ el2,
                                              const float* __restrict__ er2,
                                              const float* __restrict__ b2,
                                              float* __restrict__ out) {
    int wid = threadIdx.x >> 6;
    int n = blockIdx.x * 4 + wid;
    if (n >= N_NODES) return;
    int t = threadIdx.x & 63;
    int g = t >> 2, l = t & 3;
    int e0 = off[n], e1 = off[n + 1];
    int deg = e1 - e0;
    int niter = (deg + 15) >> 4;         // wave-uniform
    float ern = er2[n];

    float a0 = 0.f, a1 = 0.f, a2 = 0.f, a3 = 0.f, a4 = 0.f, a5 = 0.f, a6 = 0.f, a7 = 0.f;
    float dsum = 0.f;

    int eG = e0 + g;
    float x = 0.f;
    uint4 u = {0u,0u,0u,0u};
    if (niter > 0) {
        int ec = min(eG, N_EDGES - 1);
        int s = csr[ec];
        x = el2[s];
        u = *(const uint4*)&F2b[(size_t)s * 32 + l * 8];
    }
    for (int i = 0; i < niter; ++i) {
        float x2 = 0.f;
        uint4 u2 = {0u,0u,0u,0u};
        if (i + 1 < niter) {
            int e = eG + 16 * (i + 1);
            int ec = min(e, N_EDGES - 1);
            int s = csr[ec];
            x2 = el2[s];
            u2 = *(const uint4*)&F2b[(size_t)s * 32 + l * 8];
        }
        float w = (eG + 16 * i < e1) ? __expf(leaky(x + ern)) : 0.f;
        a0 = fmaf(w, bflo(u.x), a0); a1 = fmaf(w, bfhi(u.x), a1);
        a2 = fmaf(w, bflo(u.y), a2); a3 = fmaf(w, bfhi(u.y), a3);
        a4 = fmaf(w, bflo(u.z), a4); a5 = fmaf(w, bfhi(u.z), a5);
        a6 = fmaf(w, bflo(u.w), a6); a7 = fmaf(w, bfhi(u.w), a7);
        dsum += w;
        x = x2; u = u2;
    }
    #pragma unroll
    for (int m = 4; m <= 32; m <<= 1) {
        a0 += __shfl_xor(a0, m, 64); a1 += __shfl_xor(a1, m, 64);
        a2 += __shfl_xor(a2, m, 64); a3 += __shfl_xor(a3, m, 64);
        a4 += __shfl_xor(a4, m, 64); a5 += __shfl_xor(a5, m, 64);
        a6 += __shfl_xor(a6, m, 64); a7 += __shfl_xor(a7, m, 64);
        dsum += __shfl_xor(dsum, m, 64);
    }
    if (t < 4) {
        float inv = 1.f / (dsum + EPS_DEN);
        float4 r0, r1;
        r0.x = fmaf(a0, inv, b2[l * 8 + 0]);
        r0.y = fmaf(a1, inv, b2[l * 8 + 1]);
        r0.z = fmaf(a2, inv, b2[l * 8 + 2]);
        r0.w = fmaf(a3, inv, b2[l * 8 + 3]);
        r1.x = fmaf(a4, inv, b2[l * 8 + 4]);
        r1.y = fmaf(a5, inv, b2[l * 8 + 5]);
        r1.z = fmaf(a6, inv, b2[l * 8 + 6]);
        r1.w = fmaf(a7, inv, b2[l * 8 + 7]);
        *(float4*)&out[(size_t)n * 32 + l * 8]     = r0;
        *(float4*)&out[(size_t)n * 32 + l * 8 + 4] = r1;
    }
}

// ---------------- launch ----------------

extern "C" void kernel_launch(void* const* d_in, const int* in_sizes, int n_in,
                              void* d_out, int out_size, void* d_ws, size_t ws_size,
                              hipStream_t stream) {
    const float* h   = (const float*)d_in[0];
    const float* W1  = (const float*)d_in[1];
    const float* al1 = (const float*)d_in[2];
    const float* ar1 = (const float*)d_in[3];
    const float* b1  = (const float*)d_in[4];
    const float* W2  = (const float*)d_in[5];
    const float* al2 = (const float*)d_in[6];
    const float* ar2 = (const float*)d_in[7];
    const float* b2  = (const float*)d_in[8];
    const int* src   = (const int*)d_in[9];
    const int* dst   = (const int*)d_in[10];
    float* out = (float*)d_out;

    char* wsb = (char*)d_ws;
    size_t o = 0;
    auto alloc = [&](size_t bytes) {
        void* p = wsb + o;
        o += (bytes + 255) & ~(size_t)255;
        return p;
    };
    int* deg     = (int*)alloc((size_t)N_NODES * 4);
    int* off     = (int*)alloc((size_t)(N_NODES + 1) * 4);
    int* cursor  = (int*)alloc((size_t)N_NODES * 4);
    int* csr     = (int*)alloc((size_t)N_EDGES * 4);
    int* bsum    = (int*)alloc((size_t)NB_SCAN * 4);
    unsigned short* Wt     = (unsigned short*)alloc((size_t)128 * 256 * 2);
    unsigned short* feat1b = (unsigned short*)alloc((size_t)N_NODES * 128 * 2);
    float* el1   = (float*)alloc((size_t)N_NODES * 4 * 4);
    float* er1   = (float*)alloc((size_t)N_NODES * 4 * 4);
    unsigned short* feat2b = (unsigned short*)alloc((size_t)N_NODES * 32 * 2);
    float* el2   = (float*)alloc((size_t)N_NODES * 4);
    float* er2   = (float*)alloc((size_t)N_NODES * 4);

    init_k<<<NB_INIT, 256, 0, stream>>>(deg, W1, Wt);
    gemmA_count_k<<<NB_GA + NB_EDGE, 256, 0, stream>>>(h, Wt, al1, ar1, feat1b,
                                                       el1, er1, dst, deg);
    scan1_k<<<NB_SCAN, 256, 0, stream>>>(deg, off, bsum);
    scan3_k<<<(N_NODES + 255) / 256, 256, 0, stream>>>(off, cursor, bsum);
    gemmB_scatter_k<<<NB_GB + NB_EDGE, 256, 0, stream>>>(h, Wt, al1, ar1, feat1b,
                                                         el1, er1, src, dst, cursor, csr);
    agg1_k<<<N_NODES / 2, 256, 0, stream>>>(feat1b, off, csr, el1, er1, b1, W2,
                                            al2, ar2, feat2b, el2, er2);
    agg2_k<<<(N_NODES + 3) / 4, 256, 0, stream>>>(feat2b, off, csr, el2, er2, b2, out);
}

// Round 16
// 162.614 us; speedup vs baseline: 1.1881x; 1.1742x over previous
//
#include <hip/hip_runtime.h>
#include <hip/hip_bf16.h>
#include <math.h>

#define N_NODES 50000
#define N_EDGES 800000
#define NEG_SLOPE 0.2f
#define EPS_DEN 1e-9f

constexpr int SCAN_BLK = 1024;
constexpr int NB_SCAN = (N_NODES + SCAN_BLK - 1) / SCAN_BLK;   // 49
constexpr int NB_EDGE = (N_EDGES + 255) / 256;                  // 3125
constexpr int ROWS_A  = 25024;                                  // half-A rows (64-aligned)
constexpr int NB_GA   = ROWS_A / 64;                            // 391
constexpr int NB_GB   = (N_NODES - ROWS_A + 63) / 64;           // 391
constexpr int NB_INIT = (N_NODES + 255) / 256;                  // 196 (>= 128 for Wt)

typedef __attribute__((ext_vector_type(8))) short short8v;
typedef __attribute__((ext_vector_type(4))) float f32x4;

__device__ inline unsigned short f2bf(float x) {
    __hip_bfloat16 h = __float2bfloat16(x);
    return *(unsigned short*)&h;
}
__device__ inline float bflo(unsigned int u) { return __uint_as_float(u << 16); }
__device__ inline float bfhi(unsigned int u) { return __uint_as_float(u & 0xffff0000u); }
__device__ inline float leaky(float x) { return x > 0.f ? x : NEG_SLOPE * x; }

// ---------------- K1: zero deg ∥ build Wt[col][k] = bf16(W1[k][col]) ----------------

__global__ void init_k(int* __restrict__ deg, const float* __restrict__ W,
                       unsigned short* __restrict__ Wt) {
    int i = blockIdx.x * 256 + threadIdx.x;
    if (i < N_NODES) deg[i] = 0;
    if (i < 128 * 256) {
        int col = i >> 8, k = i & 255;
        Wt[i] = f2bf(W[(size_t)k * 128 + col]);
    }
}

// ---------------- scan ----------------

__global__ void scan1_k(const int* __restrict__ deg, int* __restrict__ off,
                        int* __restrict__ bsum) {
    __shared__ int sh[256];
    int b = blockIdx.x, t = threadIdx.x;
    int base = b * SCAN_BLK + t * 4;
    int v[4]; int s = 0;
    #pragma unroll
    for (int i = 0; i < 4; ++i) {
        int idx = base + i;
        v[i] = (idx < N_NODES) ? deg[idx] : 0;
        s += v[i];
    }
    sh[t] = s; __syncthreads();
    for (int ofs = 1; ofs < 256; ofs <<= 1) {
        int x = 0;
        if (t >= ofs) x = sh[t - ofs];
        __syncthreads();
        sh[t] += x;
        __syncthreads();
    }
    int excl = sh[t] - s;
    if (t == 255) bsum[b] = sh[255];
    int run = excl;
    #pragma unroll
    for (int i = 0; i < 4; ++i) {
        int idx = base + i;
        if (idx < N_NODES) off[idx] = run;
        run += v[i];
    }
}

// merged scan2+scan3
__global__ void scan3_k(int* __restrict__ off, const int* __restrict__ bsum) {
    __shared__ int pre;
    int b = blockIdx.x;
    if (threadIdx.x == 0) {
        int s = 0;
        int nb = b >> 2;
        for (int j = 0; j < nb; ++j) s += bsum[j];
        pre = s;
    }
    __syncthreads();
    int i = b * 256 + threadIdx.x;
    if (i < N_NODES) off[i] += pre;
    if (i == 0) off[N_NODES] = N_EDGES;
}

// ---------------- gemm body (MFMA, zero-LDS, 64-row tile) + fused el1/er1 ----------------

__device__ inline void gemm_body(int rowBase0,
                                 const float* __restrict__ H,
                                 const unsigned short* __restrict__ Wt,
                                 const float* __restrict__ AL,
                                 const float* __restrict__ AR,
                                 unsigned short* __restrict__ Fb,
                                 float* __restrict__ el, float* __restrict__ er) {
    int t = threadIdx.x;
    int w = t >> 6, l = t & 63;
    int lr = l & 15, lk = l >> 4;
    int rowBase = rowBase0 + w * 16;
    f32x4 acc[8] = {};

    int arow = min(rowBase + lr, N_NODES - 1);     // clamp: loads unconditional
    const float4* Hrow = (const float4*)&H[(size_t)arow * 256 + lk * 8];

    float4 hv[16];
    #pragma unroll
    for (int kc = 0; kc < 8; ++kc) {
        hv[2 * kc]     = Hrow[(size_t)kc * 8];
        hv[2 * kc + 1] = Hrow[(size_t)kc * 8 + 1];
    }

    #pragma unroll
    for (int kc = 0; kc < 8; ++kc) {
        int k0 = kc * 32 + lk * 8;
        union { unsigned u[4]; short8v v; } ah, alo;
        const float* f = (const float*)&hv[2 * kc];
        #pragma unroll
        for (int j = 0; j < 4; ++j) {
            float f0 = f[2 * j], f1 = f[2 * j + 1];
            unsigned b0 = __float_as_uint(f0);
            unsigned b1 = __float_as_uint(f1);
            ah.u[j] = __builtin_amdgcn_perm(b1, b0, 0x07060302u);
            float r0 = f0 - __uint_as_float(b0 & 0xffff0000u);
            float r1 = f1 - __uint_as_float(b1 & 0xffff0000u);
            alo.u[j] = __builtin_amdgcn_perm(__float_as_uint(r1), __float_as_uint(r0),
                                             0x07060302u);
        }
        #pragma unroll
        for (int cf = 0; cf < 8; ++cf) {
            short8v b = *(const short8v*)&Wt[(size_t)(cf * 16 + lr) * 256 + k0];
            acc[cf] = __builtin_amdgcn_mfma_f32_16x16x32_bf16(ah.v,  b, acc[cf], 0, 0, 0);
            acc[cf] = __builtin_amdgcn_mfma_f32_16x16x32_bf16(alo.v, b, acc[cf], 0, 0, 0);
        }
    }

    #pragma unroll
    for (int r = 0; r < 4; ++r) {
        int row = rowBase + lk * 4 + r;
        if (row < N_NODES) {
            #pragma unroll
            for (int cf = 0; cf < 8; ++cf)
                Fb[(size_t)row * 128 + cf * 16 + lr] = f2bf(acc[cf][r]);
        }
    }

    float pel[4][4], per_[4][4];
    #pragma unroll
    for (int hh = 0; hh < 4; ++hh) {
        float a0 = AL[hh * 32 + lr], a1 = AL[hh * 32 + 16 + lr];
        float r0 = AR[hh * 32 + lr], r1 = AR[hh * 32 + 16 + lr];
        #pragma unroll
        for (int r = 0; r < 4; ++r) {
            pel[hh][r]  = acc[2 * hh][r] * a0 + acc[2 * hh + 1][r] * a1;
            per_[hh][r] = acc[2 * hh][r] * r0 + acc[2 * hh + 1][r] * r1;
        }
    }
    #pragma unroll
    for (int m = 1; m <= 8; m <<= 1) {
        #pragma unroll
        for (int hh = 0; hh < 4; ++hh)
            #pragma unroll
            for (int r = 0; r < 4; ++r) {
                pel[hh][r]  += __shfl_xor(pel[hh][r], m, 64);
                per_[hh][r] += __shfl_xor(per_[hh][r], m, 64);
            }
    }
    if (lr == 0) {
        #pragma unroll
        for (int r = 0; r < 4; ++r) {
            int row = rowBase + lk * 4 + r;
            if (row < N_NODES) {
                #pragma unroll
                for (int hh = 0; hh < 4; ++hh) {
                    el[(size_t)row * 4 + hh] = pel[hh][r];
                    er[(size_t)row * 4 + hh] = per_[hh][r];
                }
            }
        }
    }
}

// ---------------- K2: gemm half A ∥ count (stores within-node rank in perm) ----------------

__global__ __launch_bounds__(256) void gemmA_count_k(
        const float* __restrict__ H, const unsigned short* __restrict__ Wt,
        const float* __restrict__ AL, const float* __restrict__ AR,
        unsigned short* __restrict__ Fb, float* __restrict__ el, float* __restrict__ er,
        const int* __restrict__ dst, int* __restrict__ deg, int* __restrict__ perm) {
    int bx = blockIdx.x;
    if (bx < NB_GA) {
        gemm_body(bx * 64, H, Wt, AL, AR, Fb, el, er);
    } else {
        int e = (bx - NB_GA) * 256 + threadIdx.x;
        if (e < N_EDGES) perm[e] = atomicAdd(&deg[dst[e]], 1);
    }
}

// ---------------- K5: gemm half B ∥ scatter (atomic-free via rank) ----------------

__global__ __launch_bounds__(256) void gemmB_scatter_k(
        const float* __restrict__ H, const unsigned short* __restrict__ Wt,
        const float* __restrict__ AL, const float* __restrict__ AR,
        unsigned short* __restrict__ Fb, float* __restrict__ el, float* __restrict__ er,
        const int* __restrict__ src, const int* __restrict__ dst,
        const int* __restrict__ off, const int* __restrict__ perm,
        int* __restrict__ csr) {
    int bx = blockIdx.x;
    if (bx < NB_GB) {
        gemm_body(ROWS_A + bx * 64, H, Wt, AL, AR, Fb, el, er);
    } else {
        int e = (bx - NB_GB) * 256 + threadIdx.x;
        if (e < N_EDGES) csr[off[dst[e]] + perm[e]] = src[e];
    }
}

// ---------------- agg1: wave-per-node, pair-pipelined clamped gathers (round-13) ----------------
// wave lanes: g = slot 0..3, l = dim group 0..15 (dims 8l..8l+7), head l>>2.

__global__ __launch_bounds__(256) void agg1_k(const unsigned short* __restrict__ Fb,
                                              const int* __restrict__ off,
                                              const int* __restrict__ csr,
                                              const float* __restrict__ el1,
                                              const float* __restrict__ er1,
                                              const float* __restrict__ b1,
                                              const float* __restrict__ W2,
                                              const float* __restrict__ al2,
                                              const float* __restrict__ ar2,
                                              unsigned short* __restrict__ feat2b,
                                              float* __restrict__ el2,
                                              float* __restrict__ er2) {
    __shared__ float h1row[4][128];
    int wid = threadIdx.x >> 6;
    int n = blockIdx.x * 4 + wid;
    if (n >= N_NODES) return;
    int t = threadIdx.x & 63;
    int g = t >> 4;
    int l = t & 15;
    int hh = l >> 2;
    int e0 = off[n], e1 = off[n + 1];
    int deg = e1 - e0;
    int niter = (deg + 7) >> 3;          // wave-uniform
    float ern = er1[(size_t)n * 4 + hh];

    float a0 = 0.f, a1 = 0.f, a2 = 0.f, a3 = 0.f, a4 = 0.f, a5 = 0.f, a6 = 0.f, a7 = 0.f;
    float dsum = 0.f;

    int eA = e0 + g;
    float xA = 0.f, xB = 0.f;
    uint4 uA = {0u,0u,0u,0u}, uB = {0u,0u,0u,0u};
    if (niter > 0) {                      // uniform branch
        int ec = min(eA, N_EDGES - 1);
        int s = csr[ec];
        xA = el1[(size_t)s * 4 + hh];
        uA = *(const uint4*)&Fb[(size_t)s * 128 + l * 8];
        ec = min(eA + 4, N_EDGES - 1);
        s = csr[ec];
        xB = el1[(size_t)s * 4 + hh];
        uB = *(const uint4*)&Fb[(size_t)s * 128 + l * 8];
    }
    for (int i = 0; i < niter; ++i) {
        float xA2 = 0.f, xB2 = 0.f;
        uint4 uA2 = {0u,0u,0u,0u}, uB2 = {0u,0u,0u,0u};
        if (i + 1 < niter) {              // uniform branch
            int e = eA + 8 * (i + 1);
            int ec = min(e, N_EDGES - 1);
            int s = csr[ec];
            xA2 = el1[(size_t)s * 4 + hh];
            uA2 = *(const uint4*)&Fb[(size_t)s * 128 + l * 8];
            ec = min(e + 4, N_EDGES - 1);
            s = csr[ec];
            xB2 = el1[(size_t)s * 4 + hh];
            uB2 = *(const uint4*)&Fb[(size_t)s * 128 + l * 8];
        }
        int ebase = eA + 8 * i;
        float wA = (ebase     < e1) ? __expf(leaky(xA + ern)) : 0.f;
        float wB = (ebase + 4 < e1) ? __expf(leaky(xB + ern)) : 0.f;
        a0 = fmaf(wA, bflo(uA.x), a0); a1 = fmaf(wA, bfhi(uA.x), a1);
        a2 = fmaf(wA, bflo(uA.y), a2); a3 = fmaf(wA, bfhi(uA.y), a3);
        a4 = fmaf(wA, bflo(uA.z), a4); a5 = fmaf(wA, bfhi(uA.z), a5);
        a6 = fmaf(wA, bflo(uA.w), a6); a7 = fmaf(wA, bfhi(uA.w), a7);
        a0 = fmaf(wB, bflo(uB.x), a0); a1 = fmaf(wB, bfhi(uB.x), a1);
        a2 = fmaf(wB, bflo(uB.y), a2); a3 = fmaf(wB, bfhi(uB.y), a3);
        a4 = fmaf(wB, bflo(uB.z), a4); a5 = fmaf(wB, bfhi(uB.z), a5);
        a6 = fmaf(wB, bflo(uB.w), a6); a7 = fmaf(wB, bfhi(uB.w), a7);
        dsum += wA + wB;
        xA = xA2; xB = xB2; uA = uA2; uB = uB2;
    }

    #pragma unroll
    for (int m = 16; m <= 32; m <<= 1) {
        a0 += __shfl_xor(a0, m, 64); a1 += __shfl_xor(a1, m, 64);
        a2 += __shfl_xor(a2, m, 64); a3 += __shfl_xor(a3, m, 64);
        a4 += __shfl_xor(a4, m, 64); a5 += __shfl_xor(a5, m, 64);
        a6 += __shfl_xor(a6, m, 64); a7 += __shfl_xor(a7, m, 64);
        dsum += __shfl_xor(dsum, m, 64);
    }

    float inv = 1.f / (dsum + EPS_DEN);
    float o[8] = {a0, a1, a2, a3, a4, a5, a6, a7};
    #pragma unroll
    for (int j = 0; j < 8; ++j) {
        float v = fmaf(o[j], inv, b1[l * 8 + j]);
        o[j] = v > 0.f ? v : __expf(v) - 1.f;
    }
    if (g == 0) {
        *(float4*)&h1row[wid][l * 8]     = make_float4(o[0], o[1], o[2], o[3]);
        *(float4*)&h1row[wid][l * 8 + 4] = make_float4(o[4], o[5], o[6], o[7]);
    }
    // wave-coherent LDS RAW within the same wave

    // fused GEMM2, j-quad form: lane = 4 cols (jq) x 16 k's (kb2)
    int jq = (t & 7) * 4;
    int kb2 = (t >> 3) * 16;
    float p0 = 0.f, p1 = 0.f, p2 = 0.f, p3 = 0.f;
    #pragma unroll
    for (int k = 0; k < 16; ++k) {
        float hv = h1row[wid][kb2 + k];
        float4 wv = *(const float4*)&W2[(size_t)(kb2 + k) * 32 + jq];
        p0 = fmaf(hv, wv.x, p0);
        p1 = fmaf(hv, wv.y, p1);
        p2 = fmaf(hv, wv.z, p2);
        p3 = fmaf(hv, wv.w, p3);
    }
    #pragma unroll
    for (int m = 8; m <= 32; m <<= 1) {
        p0 += __shfl_xor(p0, m, 64);
        p1 += __shfl_xor(p1, m, 64);
        p2 += __shfl_xor(p2, m, 64);
        p3 += __shfl_xor(p3, m, 64);
    }
    if (t < 8) {
        ushort4 fv = {f2bf(p0), f2bf(p1), f2bf(p2), f2bf(p3)};
        *(ushort4*)&feat2b[(size_t)n * 32 + jq] = fv;
        float sl = p0 * al2[jq] + p1 * al2[jq + 1] + p2 * al2[jq + 2] + p3 * al2[jq + 3];
        float sr = p0 * ar2[jq] + p1 * ar2[jq + 1] + p2 * ar2[jq + 2] + p3 * ar2[jq + 3];
        #pragma unroll
        for (int m = 1; m <= 4; m <<= 1) {
            sl += __shfl_xor(sl, m, 64);
            sr += __shfl_xor(sr, m, 64);
        }
        if (t == 0) { el2[n] = sl; er2[n] = sr; }
    }
}

// ---------------- agg2: wave-per-node, uniform-iter clamped gathers ----------------
// 16 edge slots x 4 dim lanes (dims 8l..8l+7)

__global__ __launch_bounds__(256) void agg2_k(const unsigned short* __restrict__ F2b,
                                              const int* __restrict__ off,
                                              const int* __restrict__ csr,
                                              const float* __restrict__ el2,
                                              const float* __restrict__ er2,
                                              const float* __restrict__ b2,
                                              float* __restrict__ out) {
    int wid = threadIdx.x >> 6;
    int n = blockIdx.x * 4 + wid;
    if (n >= N_NODES) return;
    int t = threadIdx.x & 63;
    int g = t >> 2, l = t & 3;
    int e0 = off[n], e1 = off[n + 1];
    int deg = e1 - e0;
    int niter = (deg + 15) >> 4;         // wave-uniform
    float ern = er2[n];

    float a0 = 0.f, a1 = 0.f, a2 = 0.f, a3 = 0.f, a4 = 0.f, a5 = 0.f, a6 = 0.f, a7 = 0.f;
    float dsum = 0.f;

    int eG = e0 + g;
    float x = 0.f;
    uint4 u = {0u,0u,0u,0u};
    if (niter > 0) {
        int ec = min(eG, N_EDGES - 1);
        int s = csr[ec];
        x = el2[s];
        u = *(const uint4*)&F2b[(size_t)s * 32 + l * 8];
    }
    for (int i = 0; i < niter; ++i) {
        float x2 = 0.f;
        uint4 u2 = {0u,0u,0u,0u};
        if (i + 1 < niter) {
            int e = eG + 16 * (i + 1);
            int ec = min(e, N_EDGES - 1);
            int s = csr[ec];
            x2 = el2[s];
            u2 = *(const uint4*)&F2b[(size_t)s * 32 + l * 8];
        }
        float w = (eG + 16 * i < e1) ? __expf(leaky(x + ern)) : 0.f;
        a0 = fmaf(w, bflo(u.x), a0); a1 = fmaf(w, bfhi(u.x), a1);
        a2 = fmaf(w, bflo(u.y), a2); a3 = fmaf(w, bfhi(u.y), a3);
        a4 = fmaf(w, bflo(u.z), a4); a5 = fmaf(w, bfhi(u.z), a5);
        a6 = fmaf(w, bflo(u.w), a6); a7 = fmaf(w, bfhi(u.w), a7);
        dsum += w;
        x = x2; u = u2;
    }
    #pragma unroll
    for (int m = 4; m <= 32; m <<= 1) {
        a0 += __shfl_xor(a0, m, 64); a1 += __shfl_xor(a1, m, 64);
        a2 += __shfl_xor(a2, m, 64); a3 += __shfl_xor(a3, m, 64);
        a4 += __shfl_xor(a4, m, 64); a5 += __shfl_xor(a5, m, 64);
        a6 += __shfl_xor(a6, m, 64); a7 += __shfl_xor(a7, m, 64);
        dsum += __shfl_xor(dsum, m, 64);
    }
    if (t < 4) {
        float inv = 1.f / (dsum + EPS_DEN);
        float4 r0, r1;
        r0.x = fmaf(a0, inv, b2[l * 8 + 0]);
        r0.y = fmaf(a1, inv, b2[l * 8 + 1]);
        r0.z = fmaf(a2, inv, b2[l * 8 + 2]);
        r0.w = fmaf(a3, inv, b2[l * 8 + 3]);
        r1.x = fmaf(a4, inv, b2[l * 8 + 4]);
        r1.y = fmaf(a5, inv, b2[l * 8 + 5]);
        r1.z = fmaf(a6, inv, b2[l * 8 + 6]);
        r1.w = fmaf(a7, inv, b2[l * 8 + 7]);
        *(float4*)&out[(size_t)n * 32 + l * 8]     = r0;
        *(float4*)&out[(size_t)n * 32 + l * 8 + 4] = r1;
    }
}

// ---------------- launch ----------------

extern "C" void kernel_launch(void* const* d_in, const int* in_sizes, int n_in,
                              void* d_out, int out_size, void* d_ws, size_t ws_size,
                              hipStream_t stream) {
    const float* h   = (const float*)d_in[0];
    const float* W1  = (const float*)d_in[1];
    const float* al1 = (const float*)d_in[2];
    const float* ar1 = (const float*)d_in[3];
    const float* b1  = (const float*)d_in[4];
    const float* W2  = (const float*)d_in[5];
    const float* al2 = (const float*)d_in[6];
    const float* ar2 = (const float*)d_in[7];
    const float* b2  = (const float*)d_in[8];
    const int* src   = (const int*)d_in[9];
    const int* dst   = (const int*)d_in[10];
    float* out = (float*)d_out;

    char* wsb = (char*)d_ws;
    size_t o = 0;
    auto alloc = [&](size_t bytes) {
        void* p = wsb + o;
        o += (bytes + 255) & ~(size_t)255;
        return p;
    };
    int* deg     = (int*)alloc((size_t)N_NODES * 4);
    int* off     = (int*)alloc((size_t)(N_NODES + 1) * 4);
    int* perm    = (int*)alloc((size_t)N_EDGES * 4);
    int* csr     = (int*)alloc((size_t)N_EDGES * 4);
    int* bsum    = (int*)alloc((size_t)NB_SCAN * 4);
    unsigned short* Wt     = (unsigned short*)alloc((size_t)128 * 256 * 2);
    unsigned short* feat1b = (unsigned short*)alloc((size_t)N_NODES * 128 * 2);
    float* el1   = (float*)alloc((size_t)N_NODES * 4 * 4);
    float* er1   = (float*)alloc((size_t)N_NODES * 4 * 4);
    unsigned short* feat2b = (unsigned short*)alloc((size_t)N_NODES * 32 * 2);
    float* el2   = (float*)alloc((size_t)N_NODES * 4);
    float* er2   = (float*)alloc((size_t)N_NODES * 4);

    init_k<<<NB_INIT, 256, 0, stream>>>(deg, W1, Wt);
    gemmA_count_k<<<NB_GA + NB_EDGE, 256, 0, stream>>>(h, Wt, al1, ar1, feat1b,
                                                       el1, er1, dst, deg, perm);
    scan1_k<<<NB_SCAN, 256, 0, stream>>>(deg, off, bsum);
    scan3_k<<<(N_NODES + 255) / 256, 256, 0, stream>>>(off, bsum);
    gemmB_scatter_k<<<NB_GB + NB_EDGE, 256, 0, stream>>>(h, Wt, al1, ar1, feat1b,
                                                         el1, er1, src, dst, off, perm, csr);
    agg1_k<<<(N_NODES + 3) / 4, 256, 0, stream>>>(feat1b, off, csr, el1, er1, b1, W2,
                                                  al2, ar2, feat2b, el2, er2);
    agg2_k<<<(N_NODES + 3) / 4, 256, 0, stream>>>(feat2b, off, csr, el2, er2, b2, out);
}

// Round 17
// 162.013 us; speedup vs baseline: 1.1925x; 1.0037x over previous
//
#include <hip/hip_runtime.h>
#include <hip/hip_bf16.h>
#include <math.h>

#define N_NODES 50000
#define N_EDGES 800000
#define NEG_SLOPE 0.2f
#define EPS_DEN 1e-9f

constexpr int SCAN_BLK = 1024;
constexpr int NB_SCAN = (N_NODES + SCAN_BLK - 1) / SCAN_BLK;   // 49
constexpr int NB_EDGE = (N_EDGES + 255) / 256;                  // 3125
constexpr int ROWS_A  = 25024;                                  // half-A rows (64-aligned)
constexpr int NB_GA   = ROWS_A / 64;                            // 391
constexpr int NB_GB   = (N_NODES - ROWS_A + 63) / 64;           // 391
constexpr int NB_INIT = (8 * N_NODES + 255) / 256;              // 1563 (>= 128 for Wt)

typedef __attribute__((ext_vector_type(8))) short short8v;
typedef __attribute__((ext_vector_type(4))) float f32x4;

__device__ inline unsigned short f2bf(float x) {
    __hip_bfloat16 h = __float2bfloat16(x);
    return *(unsigned short*)&h;
}
__device__ inline float bflo(unsigned int u) { return __uint_as_float(u << 16); }
__device__ inline float bfhi(unsigned int u) { return __uint_as_float(u & 0xffff0000u); }
__device__ inline float leaky(float x) { return x > 0.f ? x : NEG_SLOPE * x; }

// ---------------- K1: zero deg8 replicas ∥ build Wt[col][k] = bf16(W1[k][col]) ----------------

__global__ void init_k(int* __restrict__ deg8, const float* __restrict__ W,
                       unsigned short* __restrict__ Wt) {
    int i = blockIdx.x * 256 + threadIdx.x;
    if (i < 8 * N_NODES) deg8[i] = 0;
    if (i < 128 * 256) {
        int col = i >> 8, k = i & 255;
        Wt[i] = f2bf(W[(size_t)k * 128 + col]);
    }
}

// ---------------- scan (8-replica aware) ----------------

__global__ void scan1_k(const int* __restrict__ deg8, int* __restrict__ off,
                        int* __restrict__ rsum, int* __restrict__ bsum) {
    __shared__ int sh[256];
    int b = blockIdx.x, t = threadIdx.x;
    int base = b * SCAN_BLK + t * 4;
    int v[4]; int s = 0;
    #pragma unroll
    for (int i = 0; i < 4; ++i) {
        int idx = base + i;
        int tot = 0;
        if (idx < N_NODES) {
            int rs = 0;
            #pragma unroll
            for (int r = 0; r < 8; ++r) {
                rsum[r * N_NODES + idx] = rs;         // prefix of replicas < r
                rs += deg8[r * N_NODES + idx];
            }
            tot = rs;
        }
        v[i] = tot;
        s += tot;
    }
    sh[t] = s; __syncthreads();
    for (int ofs = 1; ofs < 256; ofs <<= 1) {
        int x = 0;
        if (t >= ofs) x = sh[t - ofs];
        __syncthreads();
        sh[t] += x;
        __syncthreads();
    }
    int excl = sh[t] - s;
    if (t == 255) bsum[b] = sh[255];
    int run = excl;
    #pragma unroll
    for (int i = 0; i < 4; ++i) {
        int idx = base + i;
        if (idx < N_NODES) off[idx] = run;
        run += v[i];
    }
}

// merged scan2+scan3; folds off into rsum -> offr
__global__ void scan3_k(int* __restrict__ off, int* __restrict__ rsum,
                        const int* __restrict__ bsum) {
    __shared__ int pre;
    int b = blockIdx.x;
    if (threadIdx.x == 0) {
        int s = 0;
        int nb = b >> 2;
        for (int j = 0; j < nb; ++j) s += bsum[j];
        pre = s;
    }
    __syncthreads();
    int i = b * 256 + threadIdx.x;
    if (i < N_NODES) {
        int v = off[i] + pre;
        off[i] = v;
        #pragma unroll
        for (int r = 0; r < 8; ++r) rsum[r * N_NODES + i] += v;
    }
    if (i == 0) off[N_NODES] = N_EDGES;
}

// ---------------- gemm body (MFMA, zero-LDS, 64-row tile) + fused el1/er1 ----------------

__device__ inline void gemm_body(int rowBase0,
                                 const float* __restrict__ H,
                                 const unsigned short* __restrict__ Wt,
                                 const float* __restrict__ AL,
                                 const float* __restrict__ AR,
                                 unsigned short* __restrict__ Fb,
                                 float* __restrict__ el, float* __restrict__ er) {
    int t = threadIdx.x;
    int w = t >> 6, l = t & 63;
    int lr = l & 15, lk = l >> 4;
    int rowBase = rowBase0 + w * 16;
    f32x4 acc[8] = {};

    int arow = min(rowBase + lr, N_NODES - 1);     // clamp: loads unconditional
    const float4* Hrow = (const float4*)&H[(size_t)arow * 256 + lk * 8];

    float4 hv[16];
    #pragma unroll
    for (int kc = 0; kc < 8; ++kc) {
        hv[2 * kc]     = Hrow[(size_t)kc * 8];
        hv[2 * kc + 1] = Hrow[(size_t)kc * 8 + 1];
    }

    #pragma unroll
    for (int kc = 0; kc < 8; ++kc) {
        int k0 = kc * 32 + lk * 8;
        union { unsigned u[4]; short8v v; } ah, alo;
        const float* f = (const float*)&hv[2 * kc];
        #pragma unroll
        for (int j = 0; j < 4; ++j) {
            float f0 = f[2 * j], f1 = f[2 * j + 1];
            unsigned b0 = __float_as_uint(f0);
            unsigned b1 = __float_as_uint(f1);
            ah.u[j] = __builtin_amdgcn_perm(b1, b0, 0x07060302u);
            float r0 = f0 - __uint_as_float(b0 & 0xffff0000u);
            float r1 = f1 - __uint_as_float(b1 & 0xffff0000u);
            alo.u[j] = __builtin_amdgcn_perm(__float_as_uint(r1), __float_as_uint(r0),
                                             0x07060302u);
        }
        #pragma unroll
        for (int cf = 0; cf < 8; ++cf) {
            short8v b = *(const short8v*)&Wt[(size_t)(cf * 16 + lr) * 256 + k0];
            acc[cf] = __builtin_amdgcn_mfma_f32_16x16x32_bf16(ah.v,  b, acc[cf], 0, 0, 0);
            acc[cf] = __builtin_amdgcn_mfma_f32_16x16x32_bf16(alo.v, b, acc[cf], 0, 0, 0);
        }
    }

    #pragma unroll
    for (int r = 0; r < 4; ++r) {
        int row = rowBase + lk * 4 + r;
        if (row < N_NODES) {
            #pragma unroll
            for (int cf = 0; cf < 8; ++cf)
                Fb[(size_t)row * 128 + cf * 16 + lr] = f2bf(acc[cf][r]);
        }
    }

    float pel[4][4], per_[4][4];
    #pragma unroll
    for (int hh = 0; hh < 4; ++hh) {
        float a0 = AL[hh * 32 + lr], a1 = AL[hh * 32 + 16 + lr];
        float r0 = AR[hh * 32 + lr], r1 = AR[hh * 32 + 16 + lr];
        #pragma unroll
        for (int r = 0; r < 4; ++r) {
            pel[hh][r]  = acc[2 * hh][r] * a0 + acc[2 * hh + 1][r] * a1;
            per_[hh][r] = acc[2 * hh][r] * r0 + acc[2 * hh + 1][r] * r1;
        }
    }
    #pragma unroll
    for (int m = 1; m <= 8; m <<= 1) {
        #pragma unroll
        for (int hh = 0; hh < 4; ++hh)
            #pragma unroll
            for (int r = 0; r < 4; ++r) {
                pel[hh][r]  += __shfl_xor(pel[hh][r], m, 64);
                per_[hh][r] += __shfl_xor(per_[hh][r], m, 64);
            }
    }
    if (lr == 0) {
        #pragma unroll
        for (int r = 0; r < 4; ++r) {
            int row = rowBase + lk * 4 + r;
            if (row < N_NODES) {
                #pragma unroll
                for (int hh = 0; hh < 4; ++hh) {
                    el[(size_t)row * 4 + hh] = pel[hh][r];
                    er[(size_t)row * 4 + hh] = per_[hh][r];
                }
            }
        }
    }
}

// ---------------- K2: gemm half A ∥ count (8-sharded deg; rank in perm) ----------------

__global__ __launch_bounds__(256) void gemmA_count_k(
        const float* __restrict__ H, const unsigned short* __restrict__ Wt,
        const float* __restrict__ AL, const float* __restrict__ AR,
        unsigned short* __restrict__ Fb, float* __restrict__ el, float* __restrict__ er,
        const int* __restrict__ dst, int* __restrict__ deg8, int* __restrict__ perm) {
    int bx = blockIdx.x;
    if (bx < NB_GA) {
        gemm_body(bx * 64, H, Wt, AL, AR, Fb, el, er);
    } else {
        int eb = bx - NB_GA;
        int e = eb * 256 + threadIdx.x;
        if (e < N_EDGES) {
            int r = eb & 7;
            perm[e] = atomicAdd(&deg8[r * N_NODES + dst[e]], 1);
        }
    }
}

// ---------------- K5: gemm half B ∥ scatter (atomic-free via sharded rank) ----------------

__global__ __launch_bounds__(256) void gemmB_scatter_k(
        const float* __restrict__ H, const unsigned short* __restrict__ Wt,
        const float* __restrict__ AL, const float* __restrict__ AR,
        unsigned short* __restrict__ Fb, float* __restrict__ el, float* __restrict__ er,
        const int* __restrict__ src, const int* __restrict__ dst,
        const int* __restrict__ offr, const int* __restrict__ perm,
        int* __restrict__ csr) {
    int bx = blockIdx.x;
    if (bx < NB_GB) {
        gemm_body(ROWS_A + bx * 64, H, Wt, AL, AR, Fb, el, er);
    } else {
        int e = (bx - NB_GB) * 256 + threadIdx.x;
        if (e < N_EDGES) {
            int r = (e >> 8) & 7;
            csr[offr[r * N_NODES + dst[e]] + perm[e]] = src[e];
        }
    }
}

// ---------------- agg1: wave-per-node, pair-pipelined clamped gathers (frozen) ----------------
// wave lanes: g = slot 0..3, l = dim group 0..15 (dims 8l..8l+7), head l>>2.

__global__ __launch_bounds__(256) void agg1_k(const unsigned short* __restrict__ Fb,
                                              const int* __restrict__ off,
                                              const int* __restrict__ csr,
                                              const float* __restrict__ el1,
                                              const float* __restrict__ er1,
                                              const float* __restrict__ b1,
                                              const float* __restrict__ W2,
                                              const float* __restrict__ al2,
                                              const float* __restrict__ ar2,
                                              unsigned short* __restrict__ feat2b,
                                              float* __restrict__ el2,
                                              float* __restrict__ er2) {
    __shared__ float h1row[4][128];
    int wid = threadIdx.x >> 6;
    int n = blockIdx.x * 4 + wid;
    if (n >= N_NODES) return;
    int t = threadIdx.x & 63;
    int g = t >> 4;
    int l = t & 15;
    int hh = l >> 2;
    int e0 = off[n], e1 = off[n + 1];
    int deg = e1 - e0;
    int niter = (deg + 7) >> 3;          // wave-uniform
    float ern = er1[(size_t)n * 4 + hh];

    float a0 = 0.f, a1 = 0.f, a2 = 0.f, a3 = 0.f, a4 = 0.f, a5 = 0.f, a6 = 0.f, a7 = 0.f;
    float dsum = 0.f;

    int eA = e0 + g;
    float xA = 0.f, xB = 0.f;
    uint4 uA = {0u,0u,0u,0u}, uB = {0u,0u,0u,0u};
    if (niter > 0) {                      // uniform branch
        int ec = min(eA, N_EDGES - 1);
        int s = csr[ec];
        xA = el1[(size_t)s * 4 + hh];
        uA = *(const uint4*)&Fb[(size_t)s * 128 + l * 8];
        ec = min(eA + 4, N_EDGES - 1);
        s = csr[ec];
        xB = el1[(size_t)s * 4 + hh];
        uB = *(const uint4*)&Fb[(size_t)s * 128 + l * 8];
    }
    for (int i = 0; i < niter; ++i) {
        float xA2 = 0.f, xB2 = 0.f;
        uint4 uA2 = {0u,0u,0u,0u}, uB2 = {0u,0u,0u,0u};
        if (i + 1 < niter) {              // uniform branch
            int e = eA + 8 * (i + 1);
            int ec = min(e, N_EDGES - 1);
            int s = csr[ec];
            xA2 = el1[(size_t)s * 4 + hh];
            uA2 = *(const uint4*)&Fb[(size_t)s * 128 + l * 8];
            ec = min(e + 4, N_EDGES - 1);
            s = csr[ec];
            xB2 = el1[(size_t)s * 4 + hh];
            uB2 = *(const uint4*)&Fb[(size_t)s * 128 + l * 8];
        }
        int ebase = eA + 8 * i;
        float wA = (ebase     < e1) ? __expf(leaky(xA + ern)) : 0.f;
        float wB = (ebase + 4 < e1) ? __expf(leaky(xB + ern)) : 0.f;
        a0 = fmaf(wA, bflo(uA.x), a0); a1 = fmaf(wA, bfhi(uA.x), a1);
        a2 = fmaf(wA, bflo(uA.y), a2); a3 = fmaf(wA, bfhi(uA.y), a3);
        a4 = fmaf(wA, bflo(uA.z), a4); a5 = fmaf(wA, bfhi(uA.z), a5);
        a6 = fmaf(wA, bflo(uA.w), a6); a7 = fmaf(wA, bfhi(uA.w), a7);
        a0 = fmaf(wB, bflo(uB.x), a0); a1 = fmaf(wB, bfhi(uB.x), a1);
        a2 = fmaf(wB, bflo(uB.y), a2); a3 = fmaf(wB, bfhi(uB.y), a3);
        a4 = fmaf(wB, bflo(uB.z), a4); a5 = fmaf(wB, bfhi(uB.z), a5);
        a6 = fmaf(wB, bflo(uB.w), a6); a7 = fmaf(wB, bfhi(uB.w), a7);
        dsum += wA + wB;
        xA = xA2; xB = xB2; uA = uA2; uB = uB2;
    }

    #pragma unroll
    for (int m = 16; m <= 32; m <<= 1) {
        a0 += __shfl_xor(a0, m, 64); a1 += __shfl_xor(a1, m, 64);
        a2 += __shfl_xor(a2, m, 64); a3 += __shfl_xor(a3, m, 64);
        a4 += __shfl_xor(a4, m, 64); a5 += __shfl_xor(a5, m, 64);
        a6 += __shfl_xor(a6, m, 64); a7 += __shfl_xor(a7, m, 64);
        dsum += __shfl_xor(dsum, m, 64);
    }

    float inv = 1.f / (dsum + EPS_DEN);
    float o[8] = {a0, a1, a2, a3, a4, a5, a6, a7};
    #pragma unroll
    for (int j = 0; j < 8; ++j) {
        float v = fmaf(o[j], inv, b1[l * 8 + j]);
        o[j] = v > 0.f ? v : __expf(v) - 1.f;
    }
    if (g == 0) {
        *(float4*)&h1row[wid][l * 8]     = make_float4(o[0], o[1], o[2], o[3]);
        *(float4*)&h1row[wid][l * 8 + 4] = make_float4(o[4], o[5], o[6], o[7]);
    }
    // wave-coherent LDS RAW within the same wave

    // fused GEMM2, j-quad form: lane = 4 cols (jq) x 16 k's (kb2)
    int jq = (t & 7) * 4;
    int kb2 = (t >> 3) * 16;
    float p0 = 0.f, p1 = 0.f, p2 = 0.f, p3 = 0.f;
    #pragma unroll
    for (int k = 0; k < 16; ++k) {
        float hv = h1row[wid][kb2 + k];
        float4 wv = *(const float4*)&W2[(size_t)(kb2 + k) * 32 + jq];
        p0 = fmaf(hv, wv.x, p0);
        p1 = fmaf(hv, wv.y, p1);
        p2 = fmaf(hv, wv.z, p2);
        p3 = fmaf(hv, wv.w, p3);
    }
    #pragma unroll
    for (int m = 8; m <= 32; m <<= 1) {
        p0 += __shfl_xor(p0, m, 64);
        p1 += __shfl_xor(p1, m, 64);
        p2 += __shfl_xor(p2, m, 64);
        p3 += __shfl_xor(p3, m, 64);
    }
    if (t < 8) {
        ushort4 fv = {f2bf(p0), f2bf(p1), f2bf(p2), f2bf(p3)};
        *(ushort4*)&feat2b[(size_t)n * 32 + jq] = fv;
        float sl = p0 * al2[jq] + p1 * al2[jq + 1] + p2 * al2[jq + 2] + p3 * al2[jq + 3];
        float sr = p0 * ar2[jq] + p1 * ar2[jq + 1] + p2 * ar2[jq + 2] + p3 * ar2[jq + 3];
        #pragma unroll
        for (int m = 1; m <= 4; m <<= 1) {
            sl += __shfl_xor(sl, m, 64);
            sr += __shfl_xor(sr, m, 64);
        }
        if (t == 0) { el2[n] = sl; er2[n] = sr; }
    }
}

// ---------------- agg2: wave-per-node, uniform-iter clamped gathers ----------------
// 16 edge slots x 4 dim lanes (dims 8l..8l+7)

__global__ __launch_bounds__(256) void agg2_k(const unsigned short* __restrict__ F2b,
                                              const int* __restrict__ off,
                                              const int* __restrict__ csr,
                                              const float* __restrict__ el2,
                                              const float* __restrict__ er2,
                                              const float* __restrict__ b2,
                                              float* __restrict__ out) {
    int wid = threadIdx.x >> 6;
    int n = blockIdx.x * 4 + wid;
    if (n >= N_NODES) return;
    int t = threadIdx.x & 63;
    int g = t >> 2, l = t & 3;
    int e0 = off[n], e1 = off[n + 1];
    int deg = e1 - e0;
    int niter = (deg + 15) >> 4;         // wave-uniform
    float ern = er2[n];

    float a0 = 0.f, a1 = 0.f, a2 = 0.f, a3 = 0.f, a4 = 0.f, a5 = 0.f, a6 = 0.f, a7 = 0.f;
    float dsum = 0.f;

    int eG = e0 + g;
    float x = 0.f;
    uint4 u = {0u,0u,0u,0u};
    if (niter > 0) {
        int ec = min(eG, N_EDGES - 1);
        int s = csr[ec];
        x = el2[s];
        u = *(const uint4*)&F2b[(size_t)s * 32 + l * 8];
    }
    for (int i = 0; i < niter; ++i) {
        float x2 = 0.f;
        uint4 u2 = {0u,0u,0u,0u};
        if (i + 1 < niter) {
            int e = eG + 16 * (i + 1);
            int ec = min(e, N_EDGES - 1);
            int s = csr[ec];
            x2 = el2[s];
            u2 = *(const uint4*)&F2b[(size_t)s * 32 + l * 8];
        }
        float w = (eG + 16 * i < e1) ? __expf(leaky(x + ern)) : 0.f;
        a0 = fmaf(w, bflo(u.x), a0); a1 = fmaf(w, bfhi(u.x), a1);
        a2 = fmaf(w, bflo(u.y), a2); a3 = fmaf(w, bfhi(u.y), a3);
        a4 = fmaf(w, bflo(u.z), a4); a5 = fmaf(w, bfhi(u.z), a5);
        a6 = fmaf(w, bflo(u.w), a6); a7 = fmaf(w, bfhi(u.w), a7);
        dsum += w;
        x = x2; u = u2;
    }
    #pragma unroll
    for (int m = 4; m <= 32; m <<= 1) {
        a0 += __shfl_xor(a0, m, 64); a1 += __shfl_xor(a1, m, 64);
        a2 += __shfl_xor(a2, m, 64); a3 += __shfl_xor(a3, m, 64);
        a4 += __shfl_xor(a4, m, 64); a5 += __shfl_xor(a5, m, 64);
        a6 += __shfl_xor(a6, m, 64); a7 += __shfl_xor(a7, m, 64);
        dsum += __shfl_xor(dsum, m, 64);
    }
    if (t < 4) {
        float inv = 1.f / (dsum + EPS_DEN);
        float4 r0, r1;
        r0.x = fmaf(a0, inv, b2[l * 8 + 0]);
        r0.y = fmaf(a1, inv, b2[l * 8 + 1]);
        r0.z = fmaf(a2, inv, b2[l * 8 + 2]);
        r0.w = fmaf(a3, inv, b2[l * 8 + 3]);
        r1.x = fmaf(a4, inv, b2[l * 8 + 4]);
        r1.y = fmaf(a5, inv, b2[l * 8 + 5]);
        r1.z = fmaf(a6, inv, b2[l * 8 + 6]);
        r1.w = fmaf(a7, inv, b2[l * 8 + 7]);
        *(float4*)&out[(size_t)n * 32 + l * 8]     = r0;
        *(float4*)&out[(size_t)n * 32 + l * 8 + 4] = r1;
    }
}

// ---------------- launch ----------------

extern "C" void kernel_launch(void* const* d_in, const int* in_sizes, int n_in,
                              void* d_out, int out_size, void* d_ws, size_t ws_size,
                              hipStream_t stream) {
    const float* h   = (const float*)d_in[0];
    const float* W1  = (const float*)d_in[1];
    const float* al1 = (const float*)d_in[2];
    const float* ar1 = (const float*)d_in[3];
    const float* b1  = (const float*)d_in[4];
    const float* W2  = (const float*)d_in[5];
    const float* al2 = (const float*)d_in[6];
    const float* ar2 = (const float*)d_in[7];
    const float* b2  = (const float*)d_in[8];
    const int* src   = (const int*)d_in[9];
    const int* dst   = (const int*)d_in[10];
    float* out = (float*)d_out;

    char* wsb = (char*)d_ws;
    size_t o = 0;
    auto alloc = [&](size_t bytes) {
        void* p = wsb + o;
        o += (bytes + 255) & ~(size_t)255;
        return p;
    };
    int* deg8    = (int*)alloc((size_t)8 * N_NODES * 4);
    int* rsum    = (int*)alloc((size_t)8 * N_NODES * 4);
    int* off     = (int*)alloc((size_t)(N_NODES + 1) * 4);
    int* perm    = (int*)alloc((size_t)N_EDGES * 4);
    int* csr     = (int*)alloc((size_t)N_EDGES * 4);
    int* bsum    = (int*)alloc((size_t)NB_SCAN * 4);
    unsigned short* Wt     = (unsigned short*)alloc((size_t)128 * 256 * 2);
    unsigned short* feat1b = (unsigned short*)alloc((size_t)N_NODES * 128 * 2);
    float* el1   = (float*)alloc((size_t)N_NODES * 4 * 4);
    float* er1   = (float*)alloc((size_t)N_NODES * 4 * 4);
    unsigned short* feat2b = (unsigned short*)alloc((size_t)N_NODES * 32 * 2);
    float* el2   = (float*)alloc((size_t)N_NODES * 4);
    float* er2   = (float*)alloc((size_t)N_NODES * 4);

    init_k<<<NB_INIT, 256, 0, stream>>>(deg8, W1, Wt);
    gemmA_count_k<<<NB_GA + NB_EDGE, 256, 0, stream>>>(h, Wt, al1, ar1, feat1b,
                                                       el1, er1, dst, deg8, perm);
    scan1_k<<<NB_SCAN, 256, 0, stream>>>(deg8, off, rsum, bsum);
    scan3_k<<<(N_NODES + 255) / 256, 256, 0, stream>>>(off, rsum, bsum);
    gemmB_scatter_k<<<NB_GB + NB_EDGE, 256, 0, stream>>>(h, Wt, al1, ar1, feat1b,
                                                         el1, er1, src, dst, rsum, perm, csr);
    agg1_k<<<(N_NODES + 3) / 4, 256, 0, stream>>>(feat1b, off, csr, el1, er1, b1, W2,
                                                  al2, ar2, feat2b, el2, er2);
    agg2_k<<<(N_NODES + 3) / 4, 256, 0, stream>>>(feat2b, off, csr, el2, er2, b2, out);
}